// Round 7
// baseline (100.551 us; speedup 1.0000x reference)
//
#include <hip/hip_runtime.h>
#include <hip/hip_bf16.h>

#define B_ 16
#define N_ 64
#define C_ 128
#define H_ 64
#define W_ 64
#define HW_ (H_ * W_)
#define OUT_CH_ 256
#define MAX_GRID_ 16
#define SCALE_ 0.125f

__device__ __forceinline__ unsigned int packbf2(float lo, float hi) {
  // RNE pack of two fp32 -> bf16x2 (lo in low 16 bits)
  __hip_bfloat162 h = __float22bfloat162_rn(float2{lo, hi});
  return *(unsigned int*)&h;
}

// ---------------------------------------------------------------------------
// Kernel 1: z [B, C, HW] fp32 -> zf [B, HW, C/2] bf16-pairs (u32), plus
// (blockIdx.y==16 slab) W [OUT_CH, C] -> Wt [C, OUT_CH] fp32.
// Pass 1: each thread loads float4 from channel rows (2c2, 2c2+1) (512B/
// half-wave contiguous), packs with v_cvt_pk into u32, 4x ds_write_b32.
// Pass 2: ds_read_b128 rows + 1KB/wave contiguous global stores.
// ---------------------------------------------------------------------------
__global__ __launch_bounds__(256) void transpose_kernel(
    const float* __restrict__ z, const float* __restrict__ Wm,
    unsigned int* __restrict__ zf, float* __restrict__ Wt) {
  __shared__ unsigned int tile32[128 * 65];  // [p][c2], pad 65
  const int t = threadIdx.x;

  if (blockIdx.y == 16) {   // W-transpose slab: 32 blocks, one 32x32 tile each
    float* ft = (float*)tile32;             // 32 x 33
    int x  = blockIdx.x;                    // 0..31
    int ot = x & 7, ct = x >> 3;
    int j = t & 31, i0 = t >> 5;
#pragma unroll
    for (int k = 0; k < 4; ++k) {
      int i = i0 + k * 8;
      ft[i * 33 + j] = Wm[(size_t)(ot * 32 + i) * C_ + ct * 32 + j];
    }
    __syncthreads();
#pragma unroll
    for (int k = 0; k < 4; ++k) {
      int i = i0 + k * 8;
      Wt[(size_t)(ct * 32 + i) * OUT_CH_ + ot * 32 + j] = ft[j * 33 + i];
    }
    return;
  }

  const int b  = blockIdx.y;
  const int pt = blockIdx.x;  // HW tile, 0..31
  const float* zb = z + (size_t)b * C_ * HW_ + pt * 128;
#pragma unroll
  for (int iter = 0; iter < 8; ++iter) {
    int idx = iter * 256 + t;        // 0..2047
    int c2  = idx >> 5;              // channel pair 0..63
    int p4  = (idx & 31) << 2;       // 0,4,...,124
    const float* r0 = zb + (size_t)(c2 * 2) * HW_ + p4;
    float4 a = *(const float4*)r0;
    float4 c = *(const float4*)(r0 + HW_);
    tile32[(p4 + 0) * 65 + c2] = packbf2(a.x, c.x);
    tile32[(p4 + 1) * 65 + c2] = packbf2(a.y, c.y);
    tile32[(p4 + 2) * 65 + c2] = packbf2(a.z, c.z);
    tile32[(p4 + 3) * 65 + c2] = packbf2(a.w, c.w);
  }
  __syncthreads();

  unsigned int* zfb = zf + (size_t)b * HW_ * 64 + (size_t)pt * 128 * 64;
#pragma unroll
  for (int iter = 0; iter < 8; ++iter) {
    int idx = iter * 256 + t;        // 0..2047
    int p   = idx >> 4;              // 0..127
    int q   = (idx & 15) << 2;       // 0,4,...,60
    uint4 u = *(const uint4*)&tile32[p * 65 + q];
    *(uint4*)(zfb + (size_t)p * 64 + q) = u;
  }
}

// ---------------------------------------------------------------------------
// Kernel 2: fused ROI-align + reduce + Linear. One block (512 thr = 8 waves)
// per ROI; wave w handles gy rows {w, w+8}. Lanes = 64 channel pairs.
// Depth-1 software pipeline in the gx loop: next sample's 4 corner loads
// issue before the current sample's FMAs consume, hiding one L2 round-trip
// per sample. Epilogue: 8-way LDS reduce + split-K Linear over 512 threads.
// ---------------------------------------------------------------------------
__global__ __launch_bounds__(512) void roi_fused_kernel(
    const unsigned int* __restrict__ zf,     // [B, HW, 64] bf16-pairs
    const float* __restrict__ boxes,         // [B, N, 4]
    const float* __restrict__ Wt,            // [C, OUT_CH]
    const float* __restrict__ bias,          // [OUT_CH]
    float* __restrict__ out)                 // [B*N, OUT_CH]
{
  int bid = blockIdx.x;                    // 0..1023
  int img = (bid & 7) | ((bid >> 9) << 3); // image -> XCD class
  int roi = img * N_ + ((bid >> 3) & 63);
  int t   = threadIdx.x;
  int wv  = t >> 6;        // wave 0..7
  int c2  = t & 63;        // channel pair index

  float4 bx = ((const float4*)boxes)[roi];
  float x1 = bx.x * SCALE_ - 0.5f;
  float y1 = bx.y * SCALE_ - 0.5f;
  float roi_w = bx.z * SCALE_ - 0.5f - x1;
  float roi_h = bx.w * SCALE_ - 0.5f - y1;
  float gwf = fminf(fmaxf(ceilf(roi_w), 1.0f), (float)MAX_GRID_);
  float ghf = fminf(fmaxf(ceilf(roi_h), 1.0f), (float)MAX_GRID_);
  int gw = (int)gwf;
  int gh = (int)ghf;
  float stepx = roi_w / gwf;
  float stepy = roi_h / ghf;

  const unsigned int* zb = zf + (size_t)img * (HW_ * 64) + c2;

  float acc0 = 0.0f, acc1 = 0.0f;
  for (int gy = wv; gy < gh; gy += 8) {
    float sy = y1 + ((float)gy + 0.5f) * stepy;
    float wy = (sy > -1.0f && sy < (float)H_) ? 1.0f : 0.0f;
    float cy = fmaxf(sy, 0.0f);
    int yl = (int)cy;
    yl = yl < (H_ - 1) ? yl : (H_ - 1);
    int yh = (yl + 1) < (H_ - 1) ? (yl + 1) : (H_ - 1);
    if (yl >= H_ - 1) cy = (float)yl;
    float fy = cy - (float)yl;
    float hy = 1.0f - fy;
    const unsigned int* rowl = zb + (size_t)yl * (W_ * 64);
    const unsigned int* rowh = zb + (size_t)yh * (W_ * 64);

    // --- prologue: coords + loads for gx = 0 ---
    float nfx, nhx, nm;
    int nxl, nxh;
    {
      float sx = x1 + 0.5f * stepx;
      float wx = (sx > -1.0f && sx < (float)W_) ? 1.0f : 0.0f;
      float cx = fmaxf(sx, 0.0f);
      int xl = (int)cx;
      xl = xl < (W_ - 1) ? xl : (W_ - 1);
      int xh = (xl + 1) < (W_ - 1) ? (xl + 1) : (W_ - 1);
      if (xl >= W_ - 1) cx = (float)xl;
      nfx = cx - (float)xl; nhx = 1.0f - nfx; nm = wy * wx;
      nxl = xl; nxh = xh;
    }
    unsigned int n11 = rowl[nxl << 6], n12 = rowl[nxh << 6];
    unsigned int n21 = rowh[nxl << 6], n22 = rowh[nxh << 6];

    for (int gx = 0; gx < gw; ++gx) {
      // consume current
      unsigned int v11 = n11, v12 = n12, v21 = n21, v22 = n22;
      float fx = nfx, hx = nhx, m = nm;

      // prefetch next (clamped dup on last iter -> cached line)
      int ngx = (gx + 1 < gw) ? gx + 1 : gx;
      {
        float sx = x1 + ((float)ngx + 0.5f) * stepx;
        float wx = (sx > -1.0f && sx < (float)W_) ? 1.0f : 0.0f;
        float cx = fmaxf(sx, 0.0f);
        int xl = (int)cx;
        xl = xl < (W_ - 1) ? xl : (W_ - 1);
        int xh = (xl + 1) < (W_ - 1) ? (xl + 1) : (W_ - 1);
        if (xl >= W_ - 1) cx = (float)xl;
        nfx = cx - (float)xl; nhx = 1.0f - nfx; nm = wy * wx;
        nxl = xl; nxh = xh;
      }
      n11 = rowl[nxl << 6]; n12 = rowl[nxh << 6];
      n21 = rowh[nxl << 6]; n22 = rowh[nxh << 6];

      float w11 = hy * hx * m, w12 = hy * fx * m;
      float w21 = fy * hx * m, w22 = fy * fx * m;
      acc0 += w11 * __uint_as_float(v11 << 16)
            + w12 * __uint_as_float(v12 << 16)
            + w21 * __uint_as_float(v21 << 16)
            + w22 * __uint_as_float(v22 << 16);
      acc1 += w11 * __uint_as_float(v11 & 0xffff0000u)
            + w12 * __uint_as_float(v12 & 0xffff0000u)
            + w21 * __uint_as_float(v21 & 0xffff0000u)
            + w22 * __uint_as_float(v22 & 0xffff0000u);
    }
  }

  __shared__ float red[8][128];
  __shared__ float feat[128];
  __shared__ float lin[2][256];
  int co = c2 << 1;
  red[wv][co]     = acc0;
  red[wv][co + 1] = acc1;
  __syncthreads();
  if (t < 128) {
    float s = (red[0][t] + red[1][t]) + (red[2][t] + red[3][t])
            + (red[4][t] + red[5][t]) + (red[6][t] + red[7][t]);
    feat[t] = s * (1.0f / (ghf * gwf));
  }
  __syncthreads();

  // Linear, split-K over 512 threads: half h sums k in [h*64, h*64+64)
  int oc   = t & 255;
  int half = t >> 8;
  const float* wp = Wt + (size_t)(half * 64) * OUT_CH_ + oc;
  const float* fp = feat + half * 64;
  float a = 0.0f;
#pragma unroll 8
  for (int k = 0; k < 64; ++k)
    a += fp[k] * wp[(size_t)k * OUT_CH_];
  lin[half][oc] = a;
  __syncthreads();
  if (t < 256)
    out[(size_t)roi * OUT_CH_ + t] = lin[0][t] + lin[1][t] + bias[t];
}

extern "C" void kernel_launch(void* const* d_in, const int* in_sizes, int n_in,
                              void* d_out, int out_size, void* d_ws, size_t ws_size,
                              hipStream_t stream) {
  const float* z     = (const float*)d_in[0];  // [B,C,H,W]
  const float* boxes = (const float*)d_in[1];  // [B,N,4]
  const float* Wm    = (const float*)d_in[2];  // [OUT_CH,C]
  const float* bias  = (const float*)d_in[3];  // [OUT_CH]
  float* out = (float*)d_out;

  char* ws = (char*)d_ws;
  unsigned int* zf = (unsigned int*)ws;                      // 16.78 MB
  float* Wt = (float*)(ws + (size_t)B_ * HW_ * C_ * 2);      // 128 KB

  transpose_kernel<<<dim3(HW_ / 128, B_ + 1), 256, 0, stream>>>(z, Wm, zf, Wt);
  roi_fused_kernel<<<B_ * N_, 512, 0, stream>>>(zf, boxes, Wt, bias, out);
}

// Round 8
// 96.192 us; speedup vs baseline: 1.0453x; 1.0453x over previous
//
#include <hip/hip_runtime.h>
#include <hip/hip_bf16.h>

#define B_ 16
#define N_ 64
#define C_ 128
#define H_ 64
#define W_ 64
#define HW_ (H_ * W_)
#define OUT_CH_ 256
#define MAX_GRID_ 16
#define SCALE_ 0.125f

__device__ __forceinline__ unsigned int packbf2(float lo, float hi) {
  __hip_bfloat162 h = __float22bfloat162_rn(float2{lo, hi});
  return *(unsigned int*)&h;
}

// ---------------------------------------------------------------------------
// Kernel 1: z [B, C, HW] fp32 -> zf [B, HW, C/2] bf16-pairs (u32), plus
// (blockIdx.y==16 slab) W [OUT_CH, C] -> Wt [C, OUT_CH] fp32.
// ---------------------------------------------------------------------------
__global__ __launch_bounds__(256) void transpose_kernel(
    const float* __restrict__ z, const float* __restrict__ Wm,
    unsigned int* __restrict__ zf, float* __restrict__ Wt) {
  __shared__ unsigned int tile32[128 * 65];  // [p][c2], pad 65
  const int t = threadIdx.x;

  if (blockIdx.y == 16) {   // W-transpose slab
    float* ft = (float*)tile32;             // 32 x 33
    int x  = blockIdx.x;                    // 0..31
    int ot = x & 7, ct = x >> 3;
    int j = t & 31, i0 = t >> 5;
#pragma unroll
    for (int k = 0; k < 4; ++k) {
      int i = i0 + k * 8;
      ft[i * 33 + j] = Wm[(size_t)(ot * 32 + i) * C_ + ct * 32 + j];
    }
    __syncthreads();
#pragma unroll
    for (int k = 0; k < 4; ++k) {
      int i = i0 + k * 8;
      Wt[(size_t)(ct * 32 + i) * OUT_CH_ + ot * 32 + j] = ft[j * 33 + i];
    }
    return;
  }

  const int b  = blockIdx.y;
  const int pt = blockIdx.x;  // HW tile, 0..31
  const float* zb = z + (size_t)b * C_ * HW_ + pt * 128;
#pragma unroll
  for (int iter = 0; iter < 8; ++iter) {
    int idx = iter * 256 + t;        // 0..2047
    int c2  = idx >> 5;              // channel pair 0..63
    int p4  = (idx & 31) << 2;       // 0,4,...,124
    const float* r0 = zb + (size_t)(c2 * 2) * HW_ + p4;
    float4 a = *(const float4*)r0;
    float4 c = *(const float4*)(r0 + HW_);
    tile32[(p4 + 0) * 65 + c2] = packbf2(a.x, c.x);
    tile32[(p4 + 1) * 65 + c2] = packbf2(a.y, c.y);
    tile32[(p4 + 2) * 65 + c2] = packbf2(a.z, c.z);
    tile32[(p4 + 3) * 65 + c2] = packbf2(a.w, c.w);
  }
  __syncthreads();

  unsigned int* zfb = zf + (size_t)b * HW_ * 64 + (size_t)pt * 128 * 64;
#pragma unroll
  for (int iter = 0; iter < 8; ++iter) {
    int idx = iter * 256 + t;        // 0..2047
    int p   = idx >> 4;              // 0..127
    int q   = (idx & 15) << 2;       // 0,4,...,60
    uint4 u = *(const uint4*)&tile32[p * 65 + q];
    *(uint4*)(zfb + (size_t)p * 64 + q) = u;
  }
}

// ---------------------------------------------------------------------------
// Kernel 2: fused ROI-align + reduce + Linear. 512 thr (8 waves) per ROI.
// Metadata (offsets + premultiplied weights) precomputed once per ROI into
// LDS. Wave w handles gy rows {w, w+8}; within a wave, lanes 0-31 process
// even gx, lanes 32-63 odd gx (2 samples/wave/iter); each lane covers 4
// channels via one dwordx2 load (512 B/wave/corner, coalesced).
// ---------------------------------------------------------------------------
__global__ __launch_bounds__(512) void roi_fused_kernel(
    const unsigned int* __restrict__ zf,     // [B, HW, 64] bf16-pairs
    const float* __restrict__ boxes,         // [B, N, 4]
    const float* __restrict__ Wt,            // [C, OUT_CH]
    const float* __restrict__ bias,          // [OUT_CH]
    float* __restrict__ out)                 // [B*N, OUT_CH]
{
  int bid = blockIdx.x;                    // 0..1023
  int img = (bid & 7) | ((bid >> 9) << 3); // image -> XCD class
  int roi = img * N_ + ((bid >> 3) & 63);
  int t   = threadIdx.x;
  int wv  = t >> 6;          // wave 0..7
  int lane = t & 63;
  int half = lane >> 5;      // gx parity
  int cq   = lane & 31;      // channel quad (4 channels)

  float4 bx = ((const float4*)boxes)[roi];
  float x1 = bx.x * SCALE_ - 0.5f;
  float y1 = bx.y * SCALE_ - 0.5f;
  float roi_w = bx.z * SCALE_ - 0.5f - x1;
  float roi_h = bx.w * SCALE_ - 0.5f - y1;
  float gwf = fminf(fmaxf(ceilf(roi_w), 1.0f), (float)MAX_GRID_);
  float ghf = fminf(fmaxf(ceilf(roi_h), 1.0f), (float)MAX_GRID_);
  int gw = (int)gwf;
  int gh = (int)ghf;
  float stepx = roi_w / gwf;
  float stepy = roi_h / ghf;

  // --- metadata build ---
  // xmeta[g] = { as_float(xl*64), as_float(xh*64), hx*vx, fx*vx }
  // ymeta[g] = { as_float(yl*W*64), as_float(yh*W*64), (1-fy)*vy, fy*vy }
  __shared__ float4 xmeta[16];
  __shared__ float4 ymeta[16];
  if (t < 16) {
    int g = t;
    float sx = x1 + ((float)g + 0.5f) * stepx;
    float v  = (g < gw && sx > -1.0f && sx < (float)W_) ? 1.0f : 0.0f;
    float cx = fmaxf(sx, 0.0f);
    int xl = (int)cx;
    xl = xl < (W_ - 1) ? xl : (W_ - 1);
    int xh = (xl + 1) < (W_ - 1) ? (xl + 1) : (W_ - 1);
    if (xl >= W_ - 1) cx = (float)xl;
    float fx = cx - (float)xl;
    float4 m;
    m.x = __int_as_float(xl << 6);
    m.y = __int_as_float(xh << 6);
    m.z = (1.0f - fx) * v;
    m.w = fx * v;
    xmeta[g] = m;
  } else if (t >= 64 && t < 80) {
    int g = t - 64;
    float sy = y1 + ((float)g + 0.5f) * stepy;
    float v  = (g < gh && sy > -1.0f && sy < (float)H_) ? 1.0f : 0.0f;
    float cy = fmaxf(sy, 0.0f);
    int yl = (int)cy;
    yl = yl < (H_ - 1) ? yl : (H_ - 1);
    int yh = (yl + 1) < (H_ - 1) ? (yl + 1) : (H_ - 1);
    if (yl >= H_ - 1) cy = (float)yl;
    float fy = cy - (float)yl;
    float4 m;
    m.x = __int_as_float(yl * (W_ * 64));
    m.y = __int_as_float(yh * (W_ * 64));
    m.z = (1.0f - fy) * v;
    m.w = fy * v;
    ymeta[g] = m;
  }
  __syncthreads();

  const unsigned int* zb = zf + (size_t)img * (HW_ * 64) + (cq << 1);

  float a0 = 0.0f, a1 = 0.0f, a2 = 0.0f, a3 = 0.0f;
  for (int gy = wv; gy < gh; gy += 8) {
    float4 ym = ymeta[gy];                 // wave-uniform broadcast
    int yloff = __float_as_int(ym.x);
    int yhoff = __float_as_int(ym.y);
    float ah = ym.z, af = ym.w;

    for (int gxp = 0; gxp < gw; gxp += 2) {
      int gx = gxp + half;                 // lane-half sample pairing
      float4 xm = xmeta[gx];
      int xloff = __float_as_int(xm.x);
      int xhoff = __float_as_int(xm.y);
      float w11 = ah * xm.z, w12 = ah * xm.w;
      float w21 = af * xm.z, w22 = af * xm.w;

      uint2 v11 = *(const uint2*)(zb + yloff + xloff);
      uint2 v12 = *(const uint2*)(zb + yloff + xhoff);
      uint2 v21 = *(const uint2*)(zb + yhoff + xloff);
      uint2 v22 = *(const uint2*)(zb + yhoff + xhoff);

      a0 += w11 * __uint_as_float(v11.x << 16)
          + w12 * __uint_as_float(v12.x << 16)
          + w21 * __uint_as_float(v21.x << 16)
          + w22 * __uint_as_float(v22.x << 16);
      a1 += w11 * __uint_as_float(v11.x & 0xffff0000u)
          + w12 * __uint_as_float(v12.x & 0xffff0000u)
          + w21 * __uint_as_float(v21.x & 0xffff0000u)
          + w22 * __uint_as_float(v22.x & 0xffff0000u);
      a2 += w11 * __uint_as_float(v11.y << 16)
          + w12 * __uint_as_float(v12.y << 16)
          + w21 * __uint_as_float(v21.y << 16)
          + w22 * __uint_as_float(v22.y << 16);
      a3 += w11 * __uint_as_float(v11.y & 0xffff0000u)
          + w12 * __uint_as_float(v12.y & 0xffff0000u)
          + w21 * __uint_as_float(v21.y & 0xffff0000u)
          + w22 * __uint_as_float(v22.y & 0xffff0000u);
    }
  }

  // --- reduce: red[16 rows][128 ch]; row = wv*2 + half, ch = 4*cq+j ---
  __shared__ float red[16][128];
  __shared__ float feat[128];
  __shared__ float lin[2][256];
  *(float4*)&red[wv * 2 + half][cq << 2] = float4{a0, a1, a2, a3};
  __syncthreads();
  if (t < 128) {
    float s = 0.0f;
#pragma unroll
    for (int r = 0; r < 16; ++r) s += red[r][t];
    feat[t] = s * (1.0f / (ghf * gwf));
  }
  __syncthreads();

  // Linear, split-K over 512 threads
  int oc = t & 255;
  int hk = t >> 8;
  const float* wp = Wt + (size_t)(hk * 64) * OUT_CH_ + oc;
  const float* fp = feat + hk * 64;
  float a = 0.0f;
#pragma unroll 8
  for (int k = 0; k < 64; ++k)
    a += fp[k] * wp[(size_t)k * OUT_CH_];
  lin[hk][oc] = a;
  __syncthreads();
  if (t < 256)
    out[(size_t)roi * OUT_CH_ + t] = lin[0][t] + lin[1][t] + bias[t];
}

extern "C" void kernel_launch(void* const* d_in, const int* in_sizes, int n_in,
                              void* d_out, int out_size, void* d_ws, size_t ws_size,
                              hipStream_t stream) {
  const float* z     = (const float*)d_in[0];  // [B,C,H,W]
  const float* boxes = (const float*)d_in[1];  // [B,N,4]
  const float* Wm    = (const float*)d_in[2];  // [OUT_CH,C]
  const float* bias  = (const float*)d_in[3];  // [OUT_CH]
  float* out = (float*)d_out;

  char* ws = (char*)d_ws;
  unsigned int* zf = (unsigned int*)ws;                      // 16.78 MB
  float* Wt = (float*)(ws + (size_t)B_ * HW_ * C_ * 2);      // 128 KB

  transpose_kernel<<<dim3(HW_ / 128, B_ + 1), 256, 0, stream>>>(z, Wm, zf, Wt);
  roi_fused_kernel<<<B_ * N_, 512, 0, stream>>>(zf, boxes, Wt, bias, out);
}